// Round 1
// baseline (860.623 us; speedup 1.0000x reference)
//
#include <hip/hip_runtime.h>

#define NN    60000
#define MMI   40000
#define NODES 100000
#define DD    64
#define NNZ   3200000
#define BB    1024
#define NEG   0.2f

// ---------------------------------------------------------------- init x = concat(eu, ei)
__global__ __launch_bounds__(256) void k_init_x(const float* __restrict__ eu,
                                                const float* __restrict__ ei,
                                                float* __restrict__ x) {
    int i = blockIdx.x * 256 + threadIdx.x;          // float4 index
    const int TOT = NODES * DD / 4;                  // 1,600,000
    if (i >= TOT) return;
    const int UE = NN * DD / 4;                      // 960,000
    float4 v = (i < UE) ? ((const float4*)eu)[i] : ((const float4*)ei)[i - UE];
    ((float4*)x)[i] = v;
}

// ---------------------------------------------------------------- CSR build
__global__ __launch_bounds__(256) void k_hist(const int* __restrict__ row,
                                              int* __restrict__ counts) {
    int e = blockIdx.x * 256 + threadIdx.x;
    if (e < NNZ) atomicAdd(&counts[row[e]], 1);
}

__global__ __launch_bounds__(1024) void k_scan1(const int* __restrict__ counts,
                                                int* __restrict__ rp,
                                                int* __restrict__ partials) {
    __shared__ int s[1024];
    int tid = threadIdx.x;
    int i = blockIdx.x * 1024 + tid;
    int v = (i < NODES) ? counts[i] : 0;
    s[tid] = v;
    __syncthreads();
    for (int off = 1; off < 1024; off <<= 1) {
        int t = (tid >= off) ? s[tid - off] : 0;
        __syncthreads();
        s[tid] += t;
        __syncthreads();
    }
    if (i < NODES) rp[i] = s[tid] - v;               // block-local exclusive
    if (tid == 1023) partials[blockIdx.x] = s[tid];  // block total
}

__global__ __launch_bounds__(128) void k_scan2(int* __restrict__ partials, int nb) {
    __shared__ int s[128];
    int tid = threadIdx.x;
    int v = (tid < nb) ? partials[tid] : 0;
    s[tid] = v;
    __syncthreads();
    for (int off = 1; off < 128; off <<= 1) {
        int t = (tid >= off) ? s[tid - off] : 0;
        __syncthreads();
        s[tid] += t;
        __syncthreads();
    }
    if (tid < nb) partials[tid] = s[tid] - v;        // exclusive
}

__global__ __launch_bounds__(1024) void k_scan3(int* __restrict__ rp,
                                                const int* __restrict__ partials,
                                                int* __restrict__ woff) {
    int i = blockIdx.x * 1024 + threadIdx.x;
    if (i < NODES) {
        int v = rp[i] + partials[i >> 10];
        rp[i] = v;
        woff[i] = v;
    }
    if (i == 0) rp[NODES] = NNZ;
}

__global__ __launch_bounds__(256) void k_scatter(const int* __restrict__ row,
                                                 const int* __restrict__ col,
                                                 const float* __restrict__ val,
                                                 int* __restrict__ woff,
                                                 int* __restrict__ cs,
                                                 float* __restrict__ vs) {
    int e = blockIdx.x * 256 + threadIdx.x;
    if (e >= NNZ) return;
    int r = row[e];
    int p = atomicAdd(&woff[r], 1);
    cs[p] = col[e];
    vs[p] = val[e];
}

// ---------------------------------------------------------------- pull SpMM: one wave / row
__global__ __launch_bounds__(256) void k_spmm(const int* __restrict__ rp,
                                              const int* __restrict__ cs,
                                              const float* __restrict__ vs,
                                              const float* __restrict__ x,
                                              float* __restrict__ lie) {
    int w    = (blockIdx.x * 256 + threadIdx.x) >> 6;
    int lane = threadIdx.x & 63;
    if (w >= NODES) return;
    int s = rp[w], e = rp[w + 1];
    float acc = 0.f;
    for (int base = s; base < e; base += 64) {
        int n = e - base; if (n > 64) n = 64;
        int c = 0; float v = 0.f;
        if (lane < n) { c = cs[base + lane]; v = vs[base + lane]; }
        int j = 0;
        for (; j + 4 <= n; j += 4) {
            int   c0 = __shfl(c, j),     c1 = __shfl(c, j + 1);
            int   c2 = __shfl(c, j + 2), c3 = __shfl(c, j + 3);
            float v0 = __shfl(v, j),     v1 = __shfl(v, j + 1);
            float v2 = __shfl(v, j + 2), v3 = __shfl(v, j + 3);
            float x0 = x[c0 * DD + lane];
            float x1 = x[c1 * DD + lane];
            float x2 = x[c2 * DD + lane];
            float x3 = x[c3 * DD + lane];
            acc += v0 * x0 + v1 * x1 + v2 * x2 + v3 * x3;
        }
        for (; j < n; ++j) {
            int cj = __shfl(c, j);
            float vj = __shfl(v, j);
            acc = fmaf(vj, x[cj * DD + lane], acc);
        }
    }
    lie[w * DD + lane] = acc;
}

// ---------------------------------------------------------------- fused layer GEMM
// x_new = leaky_relu(lie@W1 + (x*lie)@W2 + b1 + b2), in-place on x.
// 64 rows/block, 256 threads, 4x4 register tile. A tiles XOR-swizzled (f4 granularity)
// to avoid padding -> exactly 64 KB static LDS.
__global__ __launch_bounds__(256) void k_gemm(float* __restrict__ x,
                                              const float* __restrict__ lie,
                                              const float* __restrict__ W1,
                                              const float* __restrict__ W2,
                                              const float* __restrict__ b1,
                                              const float* __restrict__ b2) {
    __shared__ float A1[64 * 64];   // lie tile     (swizzled)
    __shared__ float A2[64 * 64];   // x*lie tile   (swizzled)
    __shared__ float Ws1[64 * 64];  // W1 [k][n]
    __shared__ float Ws2[64 * 64];  // W2 [k][n]

    const int t = threadIdx.x;
    const int row0 = blockIdx.x * 64;

    // stage W
    {
        const float4* w1v = (const float4*)W1;
        const float4* w2v = (const float4*)W2;
        float4* s1v = (float4*)Ws1;
        float4* s2v = (float4*)Ws2;
#pragma unroll
        for (int q = 0; q < 4; ++q) {
            s1v[q * 256 + t] = w1v[q * 256 + t];
            s2v[q * 256 + t] = w2v[q * 256 + t];
        }
    }
    // stage A tiles (swizzled: f4 group g of row r stored at g ^ (r & 15))
#pragma unroll
    for (int q = 0; q < 4; ++q) {
        int f4 = q * 256 + t;
        int rl = f4 >> 4;
        int c4 = f4 & 15;
        int gr = row0 + rl;
        float4 lv = make_float4(0.f, 0.f, 0.f, 0.f);
        float4 xv = make_float4(0.f, 0.f, 0.f, 0.f);
        if (gr < NODES) {
            lv = *(const float4*)&lie[gr * DD + c4 * 4];
            xv = *(const float4*)&x[gr * DD + c4 * 4];
        }
        int sg = c4 ^ (rl & 15);
        ((float4*)A1)[rl * 16 + sg] = lv;
        ((float4*)A2)[rl * 16 + sg] = make_float4(lv.x * xv.x, lv.y * xv.y,
                                                  lv.z * xv.z, lv.w * xv.w);
    }
    __syncthreads();

    const int tx = t & 15;   // 4-col group
    const int ty = t >> 4;   // 4-row group
    float bs[4];
    {
        float4 bb1 = *(const float4*)&b1[tx * 4];
        float4 bb2 = *(const float4*)&b2[tx * 4];
        bs[0] = bb1.x + bb2.x; bs[1] = bb1.y + bb2.y;
        bs[2] = bb1.z + bb2.z; bs[3] = bb1.w + bb2.w;
    }
    float acc[4][4];
#pragma unroll
    for (int i = 0; i < 4; ++i)
#pragma unroll
        for (int j = 0; j < 4; ++j) acc[i][j] = bs[j];

    for (int k4 = 0; k4 < 16; ++k4) {
        float4 a1[4], a2[4];
#pragma unroll
        for (int i = 0; i < 4; ++i) {
            int r = ty * 4 + i;
            int sg = k4 ^ (r & 15);
            a1[i] = ((const float4*)A1)[r * 16 + sg];
            a2[i] = ((const float4*)A2)[r * 16 + sg];
        }
#pragma unroll
        for (int kk = 0; kk < 4; ++kk) {
            float4 w1 = ((const float4*)Ws1)[(k4 * 4 + kk) * 16 + tx];
            float4 w2 = ((const float4*)Ws2)[(k4 * 4 + kk) * 16 + tx];
#pragma unroll
            for (int i = 0; i < 4; ++i) {
                float av1 = (&a1[i].x)[kk];
                float av2 = (&a2[i].x)[kk];
                acc[i][0] = fmaf(av1, w1.x, fmaf(av2, w2.x, acc[i][0]));
                acc[i][1] = fmaf(av1, w1.y, fmaf(av2, w2.y, acc[i][1]));
                acc[i][2] = fmaf(av1, w1.z, fmaf(av2, w2.z, acc[i][2]));
                acc[i][3] = fmaf(av1, w1.w, fmaf(av2, w2.w, acc[i][3]));
            }
        }
    }
    // epilogue: leaky relu, write back in place
#pragma unroll
    for (int i = 0; i < 4; ++i) {
        int gr = row0 + ty * 4 + i;
        if (gr < NODES) {
            float4 o;
            o.x = acc[i][0] >= 0.f ? acc[i][0] : NEG * acc[i][0];
            o.y = acc[i][1] >= 0.f ? acc[i][1] : NEG * acc[i][1];
            o.z = acc[i][2] >= 0.f ? acc[i][2] : NEG * acc[i][2];
            o.w = acc[i][3] >= 0.f ? acc[i][3] : NEG * acc[i][3];
            *(float4*)&x[gr * DD + tx * 4] = o;
        }
    }
}

// ---------------------------------------------------------------- gather layer repr into output
__global__ __launch_bounds__(256) void k_gather(const float* __restrict__ x,
                                                const int* __restrict__ su,
                                                const int* __restrict__ oi,
                                                const int* __restrict__ ui,
                                                float* __restrict__ out, int layer) {
    int w    = (blockIdx.x * 256 + threadIdx.x) >> 6;   // 0..3071
    int lane = threadIdx.x & 63;
    if (w >= 3 * BB) return;
    int g = w >> 10, b = w & 1023;
    int node = (g == 0) ? su[b] : (NN + ((g == 1) ? oi[b] : ui[b]));
    out[w * 256 + layer * 64 + lane] = x[node * DD + lane];
}

// ---------------------------------------------------------------- launch
extern "C" void kernel_launch(void* const* d_in, const int* in_sizes, int n_in,
                              void* d_out, int out_size, void* d_ws, size_t ws_size,
                              hipStream_t stream) {
    const int*   edge_row = (const int*)d_in[0];
    const int*   edge_col = (const int*)d_in[1];
    const float* edge_val = (const float*)d_in[2];
    const float* eu = (const float*)d_in[3];
    const float* ei = (const float*)d_in[4];
    const float* W1 = (const float*)d_in[5];
    const float* W2 = (const float*)d_in[6];
    const float* b1 = (const float*)d_in[7];
    const float* b2 = (const float*)d_in[8];
    const int*   su = (const int*)d_in[9];
    const int*   oi = (const int*)d_in[10];
    const int*   ui = (const int*)d_in[11];
    float* out = (float*)d_out;

    // workspace carve (~78.4 MB total)
    float* x        = (float*)d_ws;           // 6.4M f
    float* lie      = x + NODES * DD;         // 6.4M f
    int*   counts   = (int*)(lie + NODES * DD); // 100000
    int*   rp       = counts + NODES;         // 100001
    int*   woff     = rp + NODES + 1;         // 100000
    int*   partials = woff + NODES;           // 256
    int*   cs       = partials + 256;         // 3.2M
    float* vs       = (float*)(cs + NNZ);     // 3.2M

    hipMemsetAsync(counts, 0, NODES * sizeof(int), stream);
    k_init_x<<<(NODES * DD / 4 + 255) / 256, 256, 0, stream>>>(eu, ei, x);
    k_gather<<<(3 * BB * 64 + 255) / 256, 256, 0, stream>>>(x, su, oi, ui, out, 0);

    k_hist<<<(NNZ + 255) / 256, 256, 0, stream>>>(edge_row, counts);
    const int nb = (NODES + 1023) / 1024;     // 98
    k_scan1<<<nb, 1024, 0, stream>>>(counts, rp, partials);
    k_scan2<<<1, 128, 0, stream>>>(partials, nb);
    k_scan3<<<nb, 1024, 0, stream>>>(rp, partials, woff);
    k_scatter<<<(NNZ + 255) / 256, 256, 0, stream>>>(edge_row, edge_col, edge_val,
                                                     woff, cs, vs);

    for (int l = 0; l < 3; ++l) {
        k_spmm<<<(NODES * 64 + 255) / 256, 256, 0, stream>>>(rp, cs, vs, x, lie);
        k_gemm<<<(NODES + 63) / 64, 256, 0, stream>>>(x, lie,
                                                      W1 + l * 4096, W2 + l * 4096,
                                                      b1 + l * 64,  b2 + l * 64);
        k_gather<<<(3 * BB * 64 + 255) / 256, 256, 0, stream>>>(x, su, oi, ui, out, l + 1);
    }
}